// Round 2
// baseline (7606.669 us; speedup 1.0000x reference)
//
#include <hip/hip_runtime.h>
#include <stdint.h>

// Problem constants
#define Sn 64
#define Un 10
#define Tn 160
#define Fn 80
#define Bn 640      // S*U
#define Hn 768
#define Pn 256
#define En 256
#define G4H 3072
#define NBLK 480

using short8  = __attribute__((ext_vector_type(8))) short;
using short4v = __attribute__((ext_vector_type(4))) short;
using floatx4 = __attribute__((ext_vector_type(4))) float;

__device__ __forceinline__ short f2bf(float f){
    unsigned u = __builtin_bit_cast(unsigned, f);
    u += 0x7fffu + ((u >> 16) & 1u);
    return (short)(u >> 16);
}
__device__ __forceinline__ float bf2f(short s){
    return __builtin_bit_cast(float, ((unsigned)(unsigned short)s) << 16);
}
__device__ __forceinline__ float sigm(float x){ return 1.f / (1.f + __expf(-x)); }
__device__ __forceinline__ float tanh_(float x){
    float e = __expf(-2.f * fmaxf(x, -40.f));
    return (1.f - e) / (1.f + e);
}

// ---------------- prep: bias sums + Wih0 -> B0 tail columns -----------------
__global__ void k_prep(const float* __restrict__ Wih0,
                       const float* bi0, const float* bh0,
                       const float* bi1, const float* bh1,
                       const float* bi2, const float* bh2,
                       short* __restrict__ B0, float* __restrict__ bias){
    int i = blockIdx.x * 256 + threadIdx.x;
    const int W0 = G4H * 96;
    if (i < W0){
        int g = i / 96, c = i % 96;
        B0[(size_t)g * 864 + 768 + c] = (c < Fn) ? f2bf(Wih0[(size_t)g * Fn + c]) : (short)0;
    } else if (i < W0 + 3 * G4H){
        int j = i - W0; int l = j / G4H, g = j % G4H;
        const float* a = (l == 0) ? bi0 : (l == 1) ? bi1 : bi2;
        const float* b = (l == 0) ? bh0 : (l == 1) ? bh1 : bh2;
        bias[j] = a[g] + b[g];
    }
}

// ---------------- init: zero hidden (bf16) and c (fp32) ---------------------
__global__ void k_init(short* __restrict__ hidden, float* __restrict__ c){
    int i = blockIdx.x * 256 + threadIdx.x;
    int stride = gridDim.x * 256;
    const int NH = 3 * 2 * Bn * Hn;   // shorts
    const int NC = 3 * Bn * Hn;       // floats
    for (int j = i; j < NH; j += stride) hidden[j] = 0;
    for (int j = i; j < NC; j += stride) c[j] = 0.f;
}

// ---------------- fold: out[m][n] = sum_p A[m][p] * Whr[p][n]  (K=256) ------
__global__ void k_fold(const float* __restrict__ A, const float* __restrict__ Whr,
                       short* __restrict__ out, int ldout, int coloff, int Mtiles){
    int mt = blockIdx.x % Mtiles, nt = blockIdx.x / Mtiles;
    int lane = threadIdx.x & 63;
    int ln = lane & 15, lq = lane >> 4;
    floatx4 acc = {0.f, 0.f, 0.f, 0.f};
    const float* ap = A + (size_t)(mt * 16 + ln) * 256 + lq * 8;
    const float* bp = Whr + (size_t)(lq * 8) * 768 + nt * 16 + ln;
    for (int p0 = 0; p0 < 256; p0 += 32){
        short8 af, bf;
        #pragma unroll
        for (int j = 0; j < 8; ++j) af[j] = f2bf(ap[p0 + j]);
        #pragma unroll
        for (int j = 0; j < 8; ++j) bf[j] = f2bf(bp[(size_t)(p0 + j) * 768]);
        acc = __builtin_amdgcn_mfma_f32_16x16x32_bf16(af, bf, acc, 0, 0, 0);
    }
    #pragma unroll
    for (int r = 0; r < 4; ++r){
        int row = mt * 16 + lq * 4 + r, col = nt * 16 + ln;
        out[(size_t)row * ldout + coloff + col] = f2bf(acc[r]);
    }
}

// ---------------- per-wavefront step kernel ---------------------------------
// 480 blocks x 256 thr. layer = bid%3, r2 = bid/3: mt = r2>>4 (64 rows),
// ct = r2&15 (48 H-dims). Wave wg handles gate wg (i,f,g,o).
// hidden[layer][parity][b][j] bf16. K layout: L0: [hid_prev(768) | x(96 pad)];
// L1/2: [hid_below(768) | hid_prev(768)]. c[layer][b][j] fp32.
__global__ __launch_bounds__(256, 2) void k_step(const float* __restrict__ x,
        const short* __restrict__ B0, const short* __restrict__ B1,
        const short* __restrict__ B2, const float* __restrict__ bias,
        short* __restrict__ hidden, float* __restrict__ c, int w){
    __shared__ __align__(16) short sA[64 * 96];
    __shared__ float sEx[4 * 64 * 49];

    const int tid = threadIdx.x, lane = tid & 63, wg = tid >> 6;
    const int bid = blockIdx.x;
    const int layer = bid % 3;
    const int t = w - layer;
    if (t < 0 || t >= Tn) return;
    const int r2 = bid / 3;
    const int mt = r2 >> 4, ct = r2 & 15;
    const int m0 = mt * 64, j0 = ct * 48;
    const short* Bl = (layer == 0) ? B0 : (layer == 1) ? B1 : B2;
    const int KTOT = (layer == 0) ? 864 : 1536;
    const int NCH = KTOT / 96;
    const int ln = lane & 15, lq = lane >> 4;
    const int pp = (w + 1) & 1;   // parity written by previous wavefront

    floatx4 acc[4][3];
    #pragma unroll
    for (int nt = 0; nt < 3; ++nt){
        float bv = bias[layer * G4H + wg * Hn + j0 + nt * 16 + ln];
        #pragma unroll
        for (int m4 = 0; m4 < 4; ++m4){
            acc[m4][nt][0] = bv; acc[m4][nt][1] = bv;
            acc[m4][nt][2] = bv; acc[m4][nt][3] = bv;
        }
    }

    for (int ch = 0; ch < NCH; ++ch){
        int k0 = ch * 96;
        int rr = tid >> 2, cg = (tid & 3) * 24;
        if (ch) __syncthreads();   // protect sA from previous iteration's reads
        if (layer == 0 && ch == 8){
            const float* xr = x + ((size_t)(m0 + rr) * Tn + t) * Fn;
            #pragma unroll
            for (int ii = 0; ii < 3; ++ii){
                int f = cg + ii * 8;
                short8 v = {0,0,0,0,0,0,0,0};
                if (f < Fn){
                    float4 a = *(const float4*)(xr + f);
                    float4 b = *(const float4*)(xr + f + 4);
                    v[0]=f2bf(a.x); v[1]=f2bf(a.y); v[2]=f2bf(a.z); v[3]=f2bf(a.w);
                    v[4]=f2bf(b.x); v[5]=f2bf(b.y); v[6]=f2bf(b.z); v[7]=f2bf(b.w);
                }
                *(short8*)&sA[rr * 96 + f] = v;
            }
        } else {
            const short* src; int jj;
            if (layer == 0){ src = hidden + (size_t)pp * Bn * Hn; jj = k0; }
            else if (k0 < 768){ src = hidden + (size_t)((layer - 1) * 2 + pp) * Bn * Hn; jj = k0; }
            else { src = hidden + (size_t)(layer * 2 + pp) * Bn * Hn; jj = k0 - 768; }
            const short* srow = src + (size_t)(m0 + rr) * Hn + jj + cg;
            #pragma unroll
            for (int ii = 0; ii < 3; ++ii)
                *(short8*)&sA[rr * 96 + cg + ii * 8] = *(const short8*)&srow[ii * 8];
        }
        __syncthreads();
        #pragma unroll
        for (int ks = 0; ks < 3; ++ks){
            int kk = k0 + ks * 32 + lq * 8;
            short8 bfr[3], afr[4];
            #pragma unroll
            for (int nt = 0; nt < 3; ++nt)
                bfr[nt] = *(const short8*)&Bl[(size_t)(wg * Hn + j0 + nt * 16 + ln) * KTOT + kk];
            #pragma unroll
            for (int m4 = 0; m4 < 4; ++m4)
                afr[m4] = *(const short8*)&sA[(m4 * 16 + ln) * 96 + ks * 32 + lq * 8];
            #pragma unroll
            for (int m4 = 0; m4 < 4; ++m4)
                #pragma unroll
                for (int nt = 0; nt < 3; ++nt)
                    acc[m4][nt] = __builtin_amdgcn_mfma_f32_16x16x32_bf16(afr[m4], bfr[nt], acc[m4][nt], 0, 0, 0);
        }
    }
    __syncthreads();
    // exchange gates via LDS (wave wg holds gate wg for all 64 rows x 48 cols)
    #pragma unroll
    for (int m4 = 0; m4 < 4; ++m4)
        #pragma unroll
        for (int nt = 0; nt < 3; ++nt)
            #pragma unroll
            for (int r = 0; r < 4; ++r)
                sEx[(wg * 64 + m4 * 16 + lq * 4 + r) * 49 + nt * 16 + ln] = acc[m4][nt][r];
    __syncthreads();
    // cell update: thread -> row rr = tid>>2, cells cb..cb+11 (global c fp32)
    {
        int rr = tid >> 2, cb = (tid & 3) * 12;
        float* cp = c + ((size_t)layer * Bn + (m0 + rr)) * Hn + j0 + cb;
        short hb[12];
        #pragma unroll
        for (int ii = 0; ii < 12; ++ii){
            int cc_ = cb + ii;
            float gi = sEx[(0 * 64 + rr) * 49 + cc_];
            float gf = sEx[(1 * 64 + rr) * 49 + cc_];
            float gg = sEx[(2 * 64 + rr) * 49 + cc_];
            float go = sEx[(3 * 64 + rr) * 49 + cc_];
            float cv = sigm(gf) * cp[ii] + sigm(gi) * tanh_(gg);
            cp[ii] = cv;
            hb[ii] = f2bf(sigm(go) * tanh_(cv));
        }
        short* hp = hidden + ((size_t)(layer * 2 + (w & 1)) * Bn + (m0 + rr)) * Hn + j0 + cb;
        #pragma unroll
        for (int q = 0; q < 3; ++q){
            short4v v = {hb[q * 4 + 0], hb[q * 4 + 1], hb[q * 4 + 2], hb[q * 4 + 3]};
            *(short4v*)&hp[q * 4] = v;
        }
    }
}

// ---------------- final: emb = normalize(relu(hidden2_last @ Wf^T + b)) -----
__global__ void k_final(const short* __restrict__ h2, const short* __restrict__ Wf,
                        const float* __restrict__ blin, float* __restrict__ out){
    __shared__ __align__(16) short sH[768];
    __shared__ float sW[4];
    int b = blockIdx.x, e = threadIdx.x;
    if (e < 96) *(short8*)&sH[e * 8] = *(const short8*)&h2[(size_t)b * 768 + e * 8];
    __syncthreads();
    float acc = blin[e];
    const short* wr = Wf + (size_t)e * 768;
    for (int j = 0; j < 768; j += 8){
        short8 hv = *(const short8*)&sH[j];
        short8 wv = *(const short8*)&wr[j];
        #pragma unroll
        for (int k = 0; k < 8; ++k) acc += bf2f(hv[k]) * bf2f(wv[k]);
    }
    float v = fmaxf(acc, 0.f);
    float s = v * v;
    #pragma unroll
    for (int off = 32; off >= 1; off >>= 1) s += __shfl_down(s, off);
    if ((e & 63) == 0) sW[e >> 6] = s;
    __syncthreads();
    float tot = sW[0] + sW[1] + sW[2] + sW[3];
    float scale = 1.f / fmaxf(sqrtf(tot), 1e-12f);
    out[(size_t)b * 256 + e] = v * scale;
}

// ---------------- host launcher ---------------------------------------------
extern "C" void kernel_launch(void* const* d_in, const int* in_sizes, int n_in,
                              void* d_out, int out_size, void* d_ws, size_t ws_size,
                              hipStream_t stream){
    const float* x    = (const float*)d_in[0];
    const float* Wih0 = (const float*)d_in[1];
    const float* Whh0 = (const float*)d_in[2];
    const float* bi0  = (const float*)d_in[3];
    const float* bh0  = (const float*)d_in[4];
    const float* Whr0 = (const float*)d_in[5];
    const float* Wih1 = (const float*)d_in[6];
    const float* Whh1 = (const float*)d_in[7];
    const float* bi1  = (const float*)d_in[8];
    const float* bh1  = (const float*)d_in[9];
    const float* Whr1 = (const float*)d_in[10];
    const float* Wih2 = (const float*)d_in[11];
    const float* Whh2 = (const float*)d_in[12];
    const float* bi2  = (const float*)d_in[13];
    const float* bh2  = (const float*)d_in[14];
    const float* Whr2 = (const float*)d_in[15];
    const float* Wlin = (const float*)d_in[16];
    const float* blin = (const float*)d_in[17];

    char* wp = (char*)d_ws;
    size_t off = 0;
    auto alloc = [&](size_t bytes) -> char* {
        char* p = wp + off; off += (bytes + 255) & ~(size_t)255; return p;
    };
    short* B0   = (short*)alloc((size_t)G4H * 864 * 2);
    short* B1   = (short*)alloc((size_t)G4H * 1536 * 2);
    short* B2   = (short*)alloc((size_t)G4H * 1536 * 2);
    short* Wf   = (short*)alloc((size_t)256 * 768 * 2);
    float* bias = (float*)alloc((size_t)3 * G4H * 4);
    short* hid  = (short*)alloc((size_t)3 * 2 * Bn * Hn * 2);
    float* cst  = (float*)alloc((size_t)3 * Bn * Hn * 4);

    hipLaunchKernelGGL(k_prep, dim3(1188), dim3(256), 0, stream,
                       Wih0, bi0, bh0, bi1, bh1, bi2, bh2, B0, bias);
    hipLaunchKernelGGL(k_init, dim3(1024), dim3(256), 0, stream, hid, cst);
    // folds: R_l = Whh_l @ Whr_l ; U_l = Wih_l @ Whr_{l-1} ; Wf = Wlin @ Whr2
    hipLaunchKernelGGL(k_fold, dim3(192 * 48), dim3(64), 0, stream, Whh0, Whr0, B0, 864, 0, 192);
    hipLaunchKernelGGL(k_fold, dim3(192 * 48), dim3(64), 0, stream, Wih1, Whr0, B1, 1536, 0, 192);
    hipLaunchKernelGGL(k_fold, dim3(192 * 48), dim3(64), 0, stream, Whh1, Whr1, B1, 1536, 768, 192);
    hipLaunchKernelGGL(k_fold, dim3(192 * 48), dim3(64), 0, stream, Wih2, Whr1, B2, 1536, 0, 192);
    hipLaunchKernelGGL(k_fold, dim3(192 * 48), dim3(64), 0, stream, Whh2, Whr2, B2, 1536, 768, 192);
    hipLaunchKernelGGL(k_fold, dim3(16 * 48), dim3(64), 0, stream, Wlin, Whr2, Wf, 768, 0, 16);

    // stream-ordered wavefront pipeline: one launch per wavefront
    for (int w = 0; w < 162; ++w)
        hipLaunchKernelGGL(k_step, dim3(NBLK), dim3(256), 0, stream,
                           x, B0, B1, B2, bias, hid, cst, w);

    const short* h2 = hid + (size_t)5 * Bn * Hn;   // hidden[2][parity 1]
    hipLaunchKernelGGL(k_final, dim3(Bn), dim3(256), 0, stream, h2, Wf, blin, (float*)d_out);
}